// Round 1
// baseline (217.215 us; speedup 1.0000x reference)
//
#include <hip/hip_runtime.h>

// Problem constants: B=4, S=2048, D=768, H=12, HD=64, M=B*S=8192, K=768.
#define LOG2E 1.4426950408889634f
#define QSCALE (0.125f * LOG2E)   // HD^-0.5 * log2(e), folded into Q

typedef __attribute__((ext_vector_type(8))) __bf16 bf8_t;   // MFMA A/B frag (4 VGPR)
typedef __attribute__((ext_vector_type(4))) float f4_t;     // MFMA C/D frag

__device__ __forceinline__ unsigned short f2bf(float f) {
  unsigned int u = __float_as_uint(f);
  u += 0x7fff + ((u >> 16) & 1);          // RNE
  return (unsigned short)(u >> 16);
}

__device__ __forceinline__ void async16(const void* g, void* l) {
  __builtin_amdgcn_global_load_lds(
      (const __attribute__((address_space(1))) void*)g,
      (__attribute__((address_space(3))) void*)l, 16, 0, 0);
}

// XOR swizzle for 128B LDS rows: spreads 16 consecutive (or kt-permuted) rows
// over 8 distinct 16B slots -> 2-way conflict (free). Involution on 16B units.
__device__ __forceinline__ int swm(int r) {
  return ((r & 3) << 4) | ((r & 8) << 3);
}
__device__ __forceinline__ int swzoff(int row, int cb) {
  return (row << 7) + (cb ^ swm(row));
}

// ---------------- fp32 -> bf16 conversion ----------------
__global__ void cvt_kernel(const float* __restrict__ src,
                           unsigned short* __restrict__ dst, int n4) {
  int i = blockIdx.x * blockDim.x + threadIdx.x;
  int stride = gridDim.x * blockDim.x;
  for (; i < n4; i += stride) {
    float4 v = ((const float4*)src)[i];
    ushort4 o;
    o.x = f2bf(v.x); o.y = f2bf(v.y); o.z = f2bf(v.z); o.w = f2bf(v.w);
    ((ushort4*)dst)[i] = o;
  }
}

// ---------------- shared NT-GEMM core ----------------
// D[i][j] = sum_k A[i][k] * Bm[j][k], K=768, tile 128x128, BK=64, 4 waves 2x2.
// C/D layout: col(j) = lane&15, row(i) = (lane>>4)*4 + reg.
__device__ __forceinline__ void gemm_core(const unsigned short* __restrict__ A,
                                          const unsigned short* __restrict__ Bm,
                                          int i0, int j0,
                                          char* lsA, char* lsB,
                                          f4_t (&acc)[4][4]) {
  const int tid = threadIdx.x;
  const int l = tid & 63;
  const int wi = (tid >> 6) >> 1, wj = (tid >> 6) & 1;
  for (int k0 = 0; k0 < 768; k0 += 64) {
    // stage A/B tiles (16KB each), linear LDS dest + inverse-swizzled source
#pragma unroll
    for (int u = 0; u < 4; ++u) {
      int p = (u * 256 + tid) * 16;
      int r = p >> 7, cb = p & 127;
      int c = cb ^ swm(r);
      async16((const char*)A + ((size_t)(i0 + r) * 768 + k0) * 2 + c, lsA + p);
      async16((const char*)Bm + ((size_t)(j0 + r) * 768 + k0) * 2 + c, lsB + p);
    }
    __syncthreads();   // drains vmcnt -> tiles ready
#pragma unroll
    for (int ks = 0; ks < 2; ++ks) {
      bf8_t af[4], bfr[4];
#pragma unroll
      for (int mi = 0; mi < 4; ++mi)
        af[mi] = *(const bf8_t*)(lsA + swzoff(wi * 64 + mi * 16 + (l & 15),
                                              ks * 64 + ((l >> 4) << 4)));
#pragma unroll
      for (int nj = 0; nj < 4; ++nj)
        bfr[nj] = *(const bf8_t*)(lsB + swzoff(wj * 64 + nj * 16 + (l & 15),
                                               ks * 64 + ((l >> 4) << 4)));
#pragma unroll
      for (int mi = 0; mi < 4; ++mi)
#pragma unroll
        for (int nj = 0; nj < 4; ++nj)
          acc[mi][nj] = __builtin_amdgcn_mfma_f32_16x16x32_bf16(
              af[mi], bfr[nj], acc[mi][nj], 0, 0, 0);
    }
    __syncthreads();   // LDS reuse protection
  }
}

// ---------------- QKV projection ----------------
// z=0: Q = (x Wq^T + bq)*QSCALE -> [B,H,S,64] bf16   (A=Wq, Bm=xb, i=n, j=m)
// z=1: K = (x Wk^T + bk)        -> [B,H,S,64] bf16
// z=2: V = (x Wv^T + bv)        -> [B,H,64,S] bf16 (transposed; A=xb, Bm=Wv, i=m, j=n)
__global__ __launch_bounds__(256) void proj_qkv(
    const unsigned short* __restrict__ xb,
    const unsigned short* __restrict__ wq,
    const unsigned short* __restrict__ wk,
    const unsigned short* __restrict__ wv,
    const float* __restrict__ bq, const float* __restrict__ bk,
    const float* __restrict__ bv,
    unsigned short* __restrict__ qo, unsigned short* __restrict__ ko,
    unsigned short* __restrict__ vto) {
  __shared__ char lsA[16384], lsB[16384];
  const int bx = blockIdx.x;
  const int z = bx / 384, r = bx % 384;
  int it, jt;
  const unsigned short *A, *Bm;
  const float* bias;
  if (z == 0)      { A = wq; Bm = xb; bias = bq; it = r % 6;  jt = r / 6;  }
  else if (z == 1) { A = wk; Bm = xb; bias = bk; it = r % 6;  jt = r / 6;  }
  else             { A = xb; Bm = wv; bias = bv; it = r % 64; jt = r / 64; }
  const int i0 = it * 128, j0 = jt * 128;
  f4_t acc[4][4] = {};
  gemm_core(A, Bm, i0, j0, lsA, lsB, acc);

  const int tid = threadIdx.x, l = tid & 63;
  const int wi = (tid >> 6) >> 1, wj = (tid >> 6) & 1;
#pragma unroll
  for (int mi = 0; mi < 4; ++mi) {
#pragma unroll
    for (int nj = 0; nj < 4; ++nj) {
      int ib = i0 + wi * 64 + mi * 16 + ((l >> 4) << 2);  // i, 4 consecutive
      int j  = j0 + wj * 64 + nj * 16 + (l & 15);         // j
      f4_t v = acc[mi][nj];
      if (z < 2) {
        float4 bs = *(const float4*)(bias + ib);
        float sc = (z == 0) ? QSCALE : 1.0f;
        ushort4 o;
        o.x = f2bf((v[0] + bs.x) * sc);
        o.y = f2bf((v[1] + bs.y) * sc);
        o.z = f2bf((v[2] + bs.z) * sc);
        o.w = f2bf((v[3] + bs.w) * sc);
        int bb = j >> 11, s = j & 2047;
        int h = ib >> 6, d = ib & 63;
        unsigned short* dst = (z == 0) ? qo : ko;
        *(ushort4*)(dst + (((size_t)(bb * 12 + h) * 2048 + s) << 6) + d) = o;
      } else {
        float bvs = bias[j];
        ushort4 o;
        o.x = f2bf(v[0] + bvs); o.y = f2bf(v[1] + bvs);
        o.z = f2bf(v[2] + bvs); o.w = f2bf(v[3] + bvs);
        int bb = ib >> 11, s4 = ib & 2047;   // i is the m-dim here
        int h = j >> 6, d = j & 63;
        *(ushort4*)(vto + ((size_t)((bb * 12 + h) * 64 + d)) * 2048 + s4) = o;
      }
    }
  }
}

// ---------------- output projection: out = attn @ Wo^T + bo (fp32 out) ----------------
__global__ __launch_bounds__(256) void proj_o(
    const unsigned short* __restrict__ attnb, const unsigned short* __restrict__ wo,
    const float* __restrict__ bo, float* __restrict__ outp) {
  __shared__ char lsA[16384], lsB[16384];
  const int bx = blockIdx.x;
  const int it = bx % 6, jt = bx / 6;
  const int i0 = it * 128, j0 = jt * 128;
  f4_t acc[4][4] = {};
  gemm_core(wo, attnb, i0, j0, lsA, lsB, acc);
  const int tid = threadIdx.x, l = tid & 63;
  const int wi = (tid >> 6) >> 1, wj = (tid >> 6) & 1;
#pragma unroll
  for (int mi = 0; mi < 4; ++mi) {
#pragma unroll
    for (int nj = 0; nj < 4; ++nj) {
      int ib = i0 + wi * 64 + mi * 16 + ((l >> 4) << 2);  // n, 4 consecutive
      int j  = j0 + wj * 64 + nj * 16 + (l & 15);         // m
      float4 bs = *(const float4*)(bo + ib);
      float4 o;
      o.x = acc[mi][nj][0] + bs.x;
      o.y = acc[mi][nj][1] + bs.y;
      o.z = acc[mi][nj][2] + bs.z;
      o.w = acc[mi][nj][3] + bs.w;
      *(float4*)(outp + (size_t)j * 768 + ib) = o;
    }
  }
}

// ---------------- flash attention ----------------
// Block: 128 q rows of one (b,h); 4 waves x 32 q-cols. KV tile = 64.
// S^T = mfma(K_rows, Q_rows): C col = q (lane&15), row = kv.
// K rows fed permuted per-mfma so P lands directly in PV's B-frag layout.
__global__ __launch_bounds__(256) void attn_kernel(
    const unsigned short* __restrict__ qg,
    const unsigned short* __restrict__ kg,
    const unsigned short* __restrict__ vtg,
    unsigned short* __restrict__ attnb) {
  __shared__ char lsQ[16384];  // [128][64] bf16, swizzled
  __shared__ char lsK[8192];   // [64][64]
  __shared__ char lsV[8192];   // V^T tile: [64 d][64 kv]
  const int tid = threadIdx.x, l = tid & 63, w = tid >> 6;
  const int q0 = blockIdx.x * 128;
  const int bh = blockIdx.y;
  const size_t qkbase = (size_t)bh * 2048 * 64;
  const size_t vtbase = (size_t)bh * 64 * 2048;

  // stage Q tile
#pragma unroll
  for (int u = 0; u < 4; ++u) {
    int p = (u * 256 + tid) * 16;
    int r = p >> 7, cb = p & 127;
    int c = cb ^ swm(r);
    async16((const char*)qg + (qkbase + (size_t)(q0 + r) * 64) * 2 + c, lsQ + p);
  }
  // stage K/V tile 0
#pragma unroll
  for (int u = 0; u < 2; ++u) {
    int p = (u * 256 + tid) * 16;
    int r = p >> 7, cb = p & 127;
    int c = cb ^ swm(r);
    async16((const char*)kg + (qkbase + (size_t)r * 64) * 2 + c, lsK + p);
    async16((const char*)vtg + (vtbase + (size_t)r * 2048) * 2 + c, lsV + p);
  }
  __syncthreads();

  bf8_t qf[2][2];
#pragma unroll
  for (int qt = 0; qt < 2; ++qt)
#pragma unroll
    for (int ks = 0; ks < 2; ++ks)
      qf[qt][ks] = *(const bf8_t*)(lsQ + swzoff(w * 32 + qt * 16 + (l & 15),
                                                ks * 64 + ((l >> 4) << 4)));

  f4_t acc[4][2] = {};                 // O^T: rows d, cols q(lane&15)
  float mrun[2] = {-1e30f, -1e30f};
  float lsum[2] = {0.0f, 0.0f};

  for (int t = 0; t < 32; ++t) {
    // ---- QK^T (S^T) with permuted K-row feed ----
    f4_t sacc[4][2] = {};
#pragma unroll
    for (int kt = 0; kt < 4; ++kt) {
      int i = l & 15;
      int row = ((kt >> 1) << 5) + ((kt & 1) << 2) + ((i >> 2) << 3) + (i & 3);
#pragma unroll
      for (int ks = 0; ks < 2; ++ks) {
        bf8_t a = *(const bf8_t*)(lsK + swzoff(row, ks * 64 + ((l >> 4) << 4)));
#pragma unroll
        for (int qt = 0; qt < 2; ++qt)
          sacc[kt][qt] = __builtin_amdgcn_mfma_f32_16x16x32_bf16(
              a, qf[qt][ks], sacc[kt][qt], 0, 0, 0);
      }
    }
    // lane now holds, per qt: p for kv = 32*ks + 8*(l>>4) + (4*(kt&1)+j)

    // ---- online softmax (log2 domain; Q pre-scaled by SCALE*log2e) ----
    bf8_t pf[2][2];   // [ks][qt] : PV B-frags
#pragma unroll
    for (int qt = 0; qt < 2; ++qt) {
      float tm = -1e30f;
#pragma unroll
      for (int kt = 0; kt < 4; ++kt)
#pragma unroll
        for (int jj = 0; jj < 4; ++jj) tm = fmaxf(tm, sacc[kt][qt][jj]);
      tm = fmaxf(tm, __shfl_xor(tm, 16));
      tm = fmaxf(tm, __shfl_xor(tm, 32));
      float mnew = fmaxf(mrun[qt], tm);
      float resc = exp2f(mrun[qt] - mnew);
      mrun[qt] = mnew;
      float p[4][4];
      float ps = 0.0f;
#pragma unroll
      for (int kt = 0; kt < 4; ++kt)
#pragma unroll
        for (int jj = 0; jj < 4; ++jj) {
          p[kt][jj] = exp2f(sacc[kt][qt][jj] - mnew);
          ps += p[kt][jj];
        }
      ps += __shfl_xor(ps, 16);
      ps += __shfl_xor(ps, 32);
      lsum[qt] = lsum[qt] * resc + ps;
#pragma unroll
      for (int dt = 0; dt < 4; ++dt)
#pragma unroll
        for (int jj = 0; jj < 4; ++jj) acc[dt][qt][jj] *= resc;
      // pack: B-frag element e (k = 8*(l>>4)+e) <- p[kt=2ks+(e>>2)][e&3]
#pragma unroll
      for (int ks = 0; ks < 2; ++ks)
#pragma unroll
        for (int e = 0; e < 8; ++e)
          pf[ks][qt][e] = (__bf16)p[2 * ks + (e >> 2)][e & 3];
    }

    // ---- PV: O^T += V^T-rows x P ----
#pragma unroll
    for (int dt = 0; dt < 4; ++dt) {
      bf8_t av0 = *(const bf8_t*)(lsV + swzoff(dt * 16 + (l & 15), ((l >> 4) << 4)));
      bf8_t av1 = *(const bf8_t*)(lsV + swzoff(dt * 16 + (l & 15), 64 + ((l >> 4) << 4)));
#pragma unroll
      for (int qt = 0; qt < 2; ++qt) {
        acc[dt][qt] = __builtin_amdgcn_mfma_f32_16x16x32_bf16(av0, pf[0][qt],
                                                              acc[dt][qt], 0, 0, 0);
        acc[dt][qt] = __builtin_amdgcn_mfma_f32_16x16x32_bf16(av1, pf[1][qt],
                                                              acc[dt][qt], 0, 0, 0);
      }
    }
    __syncthreads();            // done reading K/V LDS
    if (t < 31) {
      int kv0 = (t + 1) * 64;
#pragma unroll
      for (int u = 0; u < 2; ++u) {
        int p = (u * 256 + tid) * 16;
        int r = p >> 7, cb = p & 127;
        int c = cb ^ swm(r);
        async16((const char*)kg + (qkbase + (size_t)(kv0 + r) * 64) * 2 + c, lsK + p);
        async16((const char*)vtg + (vtbase + (size_t)r * 2048 + kv0) * 2 + c, lsV + p);
      }
      __syncthreads();          // drain staging
    }
  }

  // ---- epilogue: attn_out[b][s][h*64+d] = O^T / lsum ----
  const int bb = bh / 12, h = bh % 12;
#pragma unroll
  for (int qt = 0; qt < 2; ++qt) {
    float inv = 1.0f / lsum[qt];
    int s = q0 + w * 32 + qt * 16 + (l & 15);
#pragma unroll
    for (int dt = 0; dt < 4; ++dt) {
      int dg = h * 64 + dt * 16 + ((l >> 4) << 2);
      ushort4 o;
      o.x = f2bf(acc[dt][qt][0] * inv);
      o.y = f2bf(acc[dt][qt][1] * inv);
      o.z = f2bf(acc[dt][qt][2] * inv);
      o.w = f2bf(acc[dt][qt][3] * inv);
      *(ushort4*)(attnb + ((size_t)(bb * 2048 + s)) * 768 + dg) = o;
    }
  }
}

extern "C" void kernel_launch(void* const* d_in, const int* in_sizes, int n_in,
                              void* d_out, int out_size, void* d_ws, size_t ws_size,
                              hipStream_t stream) {
  const float* x  = (const float*)d_in[0];
  const float* Wq = (const float*)d_in[1];
  const float* bq = (const float*)d_in[2];
  const float* Wk = (const float*)d_in[3];
  const float* bk = (const float*)d_in[4];
  const float* Wv = (const float*)d_in[5];
  const float* bv = (const float*)d_in[6];
  const float* Wo = (const float*)d_in[7];
  const float* bo = (const float*)d_in[8];

  const size_t XB_ELEMS = (size_t)8192 * 768;   // 6291456
  const size_t W_ELEMS  = (size_t)768 * 768;    // 589824
  unsigned short* xb  = (unsigned short*)d_ws;
  unsigned short* wqb = xb  + XB_ELEMS;
  unsigned short* wkb = wqb + W_ELEMS;
  unsigned short* wvb = wkb + W_ELEMS;
  unsigned short* wob = wvb + W_ELEMS;
  unsigned short* qb  = wob + W_ELEMS;
  unsigned short* kb  = qb  + XB_ELEMS;
  unsigned short* vtb = kb  + XB_ELEMS;
  unsigned short* attnb = xb;   // alias: xb dead after proj_qkv

  cvt_kernel<<<2048, 256, 0, stream>>>(x,  xb,  (int)(XB_ELEMS / 4));
  cvt_kernel<<<576,  256, 0, stream>>>(Wq, wqb, (int)(W_ELEMS / 4));
  cvt_kernel<<<576,  256, 0, stream>>>(Wk, wkb, (int)(W_ELEMS / 4));
  cvt_kernel<<<576,  256, 0, stream>>>(Wv, wvb, (int)(W_ELEMS / 4));
  cvt_kernel<<<576,  256, 0, stream>>>(Wo, wob, (int)(W_ELEMS / 4));

  proj_qkv<<<1152, 256, 0, stream>>>(xb, wqb, wkb, wvb, bq, bk, bv, qb, kb, vtb);
  attn_kernel<<<dim3(16, 48), 256, 0, stream>>>(qb, kb, vtb, attnb);
  proj_o<<<384, 256, 0, stream>>>(attnb, wob, bo, (float*)d_out);
}

// Round 2
// 177.542 us; speedup vs baseline: 1.2235x; 1.2235x over previous
//
#include <hip/hip_runtime.h>

// Problem constants: B=4, S=2048, D=768, H=12, HD=64, M=B*S=8192, K=768.
#define LOG2E 1.4426950408889634f
#define QSCALE (0.125f * LOG2E)   // HD^-0.5 * log2(e), folded into Q

typedef __attribute__((ext_vector_type(8))) __bf16 bf8_t;   // MFMA A/B frag (4 VGPR)
typedef __attribute__((ext_vector_type(4))) float f4_t;     // MFMA C/D frag

__device__ __forceinline__ unsigned short f2bf(float f) {
  unsigned int u = __float_as_uint(f);
  u += 0x7fff + ((u >> 16) & 1);          // RNE
  return (unsigned short)(u >> 16);
}

__device__ __forceinline__ void async16(const void* g, void* l) {
  __builtin_amdgcn_global_load_lds(
      (const __attribute__((address_space(1))) void*)g,
      (__attribute__((address_space(3))) void*)l, 16, 0, 0);
}

// XOR swizzle for 128B LDS rows: spreads 16 consecutive (or kt-permuted) rows
// over 8 distinct 16B slots -> 2-way conflict (free). Involution on 16B units.
__device__ __forceinline__ int swm(int r) {
  return ((r & 3) << 4) | ((r & 8) << 3);
}
__device__ __forceinline__ int swzoff(int row, int cb) {
  return (row << 7) + (cb ^ swm(row));
}

// ---------------- fp32 -> bf16 conversion ----------------
__global__ void cvt_kernel(const float* __restrict__ src,
                           unsigned short* __restrict__ dst, int n4) {
  int i = blockIdx.x * blockDim.x + threadIdx.x;
  int stride = gridDim.x * blockDim.x;
  for (; i < n4; i += stride) {
    float4 v = ((const float4*)src)[i];
    ushort4 o;
    o.x = f2bf(v.x); o.y = f2bf(v.y); o.z = f2bf(v.z); o.w = f2bf(v.w);
    ((ushort4*)dst)[i] = o;
  }
}

// 4 weight matrices in one launch (blockIdx.y selects)
__global__ void cvt4_kernel(const float* __restrict__ s0, const float* __restrict__ s1,
                            const float* __restrict__ s2, const float* __restrict__ s3,
                            unsigned short* __restrict__ d0, unsigned short* __restrict__ d1,
                            unsigned short* __restrict__ d2, unsigned short* __restrict__ d3,
                            int n4) {
  int z = blockIdx.y;
  const float* s = (z == 0) ? s0 : (z == 1) ? s1 : (z == 2) ? s2 : s3;
  unsigned short* d = (z == 0) ? d0 : (z == 1) ? d1 : (z == 2) ? d2 : d3;
  int i = blockIdx.x * blockDim.x + threadIdx.x;
  int stride = gridDim.x * blockDim.x;
  for (; i < n4; i += stride) {
    float4 v = ((const float4*)s)[i];
    ushort4 o;
    o.x = f2bf(v.x); o.y = f2bf(v.y); o.z = f2bf(v.z); o.w = f2bf(v.w);
    ((ushort4*)d)[i] = o;
  }
}

// ---------------- shared NT-GEMM core ----------------
// D[i][j] = sum_k A[i][k] * Bm[j][k], K=768, tile 128x128, BK=64, 4 waves 2x2.
// C/D layout: col(j) = lane&15, row(i) = (lane>>4)*4 + reg.
__device__ __forceinline__ void gemm_core(const unsigned short* __restrict__ A,
                                          const unsigned short* __restrict__ Bm,
                                          int i0, int j0,
                                          char* lsA, char* lsB,
                                          f4_t (&acc)[4][4]) {
  const int tid = threadIdx.x;
  const int l = tid & 63;
  const int wi = (tid >> 6) >> 1, wj = (tid >> 6) & 1;
  for (int k0 = 0; k0 < 768; k0 += 64) {
    // stage A/B tiles (16KB each), linear LDS dest + inverse-swizzled source
#pragma unroll
    for (int u = 0; u < 4; ++u) {
      int p = (u * 256 + tid) * 16;
      int r = p >> 7, cb = p & 127;
      int c = cb ^ swm(r);
      async16((const char*)A + ((size_t)(i0 + r) * 768 + k0) * 2 + c, lsA + p);
      async16((const char*)Bm + ((size_t)(j0 + r) * 768 + k0) * 2 + c, lsB + p);
    }
    __syncthreads();   // drains vmcnt -> tiles ready
#pragma unroll
    for (int ks = 0; ks < 2; ++ks) {
      bf8_t af[4], bfr[4];
#pragma unroll
      for (int mi = 0; mi < 4; ++mi)
        af[mi] = *(const bf8_t*)(lsA + swzoff(wi * 64 + mi * 16 + (l & 15),
                                              ks * 64 + ((l >> 4) << 4)));
#pragma unroll
      for (int nj = 0; nj < 4; ++nj)
        bfr[nj] = *(const bf8_t*)(lsB + swzoff(wj * 64 + nj * 16 + (l & 15),
                                               ks * 64 + ((l >> 4) << 4)));
#pragma unroll
      for (int mi = 0; mi < 4; ++mi)
#pragma unroll
        for (int nj = 0; nj < 4; ++nj)
          acc[mi][nj] = __builtin_amdgcn_mfma_f32_16x16x32_bf16(
              af[mi], bfr[nj], acc[mi][nj], 0, 0, 0);
    }
    __syncthreads();   // LDS reuse protection
  }
}

// ---------------- QKV projection ----------------
// z=0: Q = (x Wq^T + bq)*QSCALE -> [B,H,S,64] bf16   (A=Wq, Bm=xb, i=n, j=m)
// z=1: K = (x Wk^T + bk)        -> [B,H,S,64] bf16
// z=2: V = (x Wv^T + bv)        -> [B,H,64,S] bf16 (transposed; A=xb, Bm=Wv, i=m, j=n)
__global__ __launch_bounds__(256) void proj_qkv(
    const unsigned short* __restrict__ xb,
    const unsigned short* __restrict__ wq,
    const unsigned short* __restrict__ wk,
    const unsigned short* __restrict__ wv,
    const float* __restrict__ bq, const float* __restrict__ bk,
    const float* __restrict__ bv,
    unsigned short* __restrict__ qo, unsigned short* __restrict__ ko,
    unsigned short* __restrict__ vto) {
  __shared__ char lsA[16384], lsB[16384];
  const int bx = blockIdx.x;
  const int z = bx / 384, r = bx % 384;
  int it, jt;
  const unsigned short *A, *Bm;
  const float* bias;
  if (z == 0)      { A = wq; Bm = xb; bias = bq; it = r % 6;  jt = r / 6;  }
  else if (z == 1) { A = wk; Bm = xb; bias = bk; it = r % 6;  jt = r / 6;  }
  else             { A = xb; Bm = wv; bias = bv; it = r % 64; jt = r / 64; }
  const int i0 = it * 128, j0 = jt * 128;
  f4_t acc[4][4] = {};
  gemm_core(A, Bm, i0, j0, lsA, lsB, acc);

  const int tid = threadIdx.x, l = tid & 63;
  const int wi = (tid >> 6) >> 1, wj = (tid >> 6) & 1;
#pragma unroll
  for (int mi = 0; mi < 4; ++mi) {
#pragma unroll
    for (int nj = 0; nj < 4; ++nj) {
      int ib = i0 + wi * 64 + mi * 16 + ((l >> 4) << 2);  // i, 4 consecutive
      int j  = j0 + wj * 64 + nj * 16 + (l & 15);         // j
      f4_t v = acc[mi][nj];
      if (z < 2) {
        float4 bs = *(const float4*)(bias + ib);
        float sc = (z == 0) ? QSCALE : 1.0f;
        ushort4 o;
        o.x = f2bf((v[0] + bs.x) * sc);
        o.y = f2bf((v[1] + bs.y) * sc);
        o.z = f2bf((v[2] + bs.z) * sc);
        o.w = f2bf((v[3] + bs.w) * sc);
        int bb = j >> 11, s = j & 2047;
        int h = ib >> 6, d = ib & 63;
        unsigned short* dst = (z == 0) ? qo : ko;
        *(ushort4*)(dst + (((size_t)(bb * 12 + h) * 2048 + s) << 6) + d) = o;
      } else {
        float bvs = bias[j];
        ushort4 o;
        o.x = f2bf(v[0] + bvs); o.y = f2bf(v[1] + bvs);
        o.z = f2bf(v[2] + bvs); o.w = f2bf(v[3] + bvs);
        int bb = ib >> 11, s4 = ib & 2047;   // i is the m-dim here
        int h = j >> 6, d = j & 63;
        *(ushort4*)(vto + ((size_t)((bb * 12 + h) * 64 + d)) * 2048 + s4) = o;
      }
    }
  }
}

// ---------------- output projection: out = attn @ Wo^T + bo (fp32 out) ----------------
__global__ __launch_bounds__(256) void proj_o(
    const unsigned short* __restrict__ attnb, const unsigned short* __restrict__ wo,
    const float* __restrict__ bo, float* __restrict__ outp) {
  __shared__ char lsA[16384], lsB[16384];
  const int bx = blockIdx.x;
  const int it = bx % 6, jt = bx / 6;
  const int i0 = it * 128, j0 = jt * 128;
  f4_t acc[4][4] = {};
  gemm_core(wo, attnb, i0, j0, lsA, lsB, acc);
  const int tid = threadIdx.x, l = tid & 63;
  const int wi = (tid >> 6) >> 1, wj = (tid >> 6) & 1;
#pragma unroll
  for (int mi = 0; mi < 4; ++mi) {
#pragma unroll
    for (int nj = 0; nj < 4; ++nj) {
      int ib = i0 + wi * 64 + mi * 16 + ((l >> 4) << 2);  // n, 4 consecutive
      int j  = j0 + wj * 64 + nj * 16 + (l & 15);         // m
      float4 bs = *(const float4*)(bo + ib);
      float4 o;
      o.x = acc[mi][nj][0] + bs.x;
      o.y = acc[mi][nj][1] + bs.y;
      o.z = acc[mi][nj][2] + bs.z;
      o.w = acc[mi][nj][3] + bs.w;
      *(float4*)(outp + (size_t)j * 768 + ib) = o;
    }
  }
}

// ---------------- flash attention ----------------
// Block: 128 q rows of one (b,h); 4 waves x 32 q-cols. KV tile = 64, double-buffered.
// S^T = mfma(K_rows, Q_rows): C col = q (lane&15), row = kv.
// K rows fed permuted per-mfma so P lands directly in PV's B-frag layout.
__global__ __launch_bounds__(256) void attn_kernel(
    const unsigned short* __restrict__ qg,
    const unsigned short* __restrict__ kg,
    const unsigned short* __restrict__ vtg,
    unsigned short* __restrict__ attnb) {
  __shared__ char lsQ[16384];     // [128][64] bf16, swizzled
  __shared__ char lsK[2][8192];   // [64][64] double-buffered
  __shared__ char lsV[2][8192];   // V^T tile: [64 d][64 kv]
  const int tid = threadIdx.x, l = tid & 63, w = tid >> 6;
  const int q0 = blockIdx.x * 128;
  const int bh = blockIdx.y;
  const size_t qkbase = (size_t)bh * 2048 * 64;
  const size_t vtbase = (size_t)bh * 64 * 2048;

  // stage Q tile
#pragma unroll
  for (int u = 0; u < 4; ++u) {
    int p = (u * 256 + tid) * 16;
    int r = p >> 7, cb = p & 127;
    int c = cb ^ swm(r);
    async16((const char*)qg + (qkbase + (size_t)(q0 + r) * 64) * 2 + c, lsQ + p);
  }
  // stage K/V tile 0 into buf 0
#pragma unroll
  for (int u = 0; u < 2; ++u) {
    int p = (u * 256 + tid) * 16;
    int r = p >> 7, cb = p & 127;
    int c = cb ^ swm(r);
    async16((const char*)kg + (qkbase + (size_t)r * 64) * 2 + c, lsK[0] + p);
    async16((const char*)vtg + (vtbase + (size_t)r * 2048) * 2 + c, lsV[0] + p);
  }
  __syncthreads();

  bf8_t qf[2][2];
#pragma unroll
  for (int qt = 0; qt < 2; ++qt)
#pragma unroll
    for (int ks = 0; ks < 2; ++ks)
      qf[qt][ks] = *(const bf8_t*)(lsQ + swzoff(w * 32 + qt * 16 + (l & 15),
                                                ks * 64 + ((l >> 4) << 4)));

  // hoisted LDS read offsets (invariant across tiles)
  int koff[4][2];
#pragma unroll
  for (int kt = 0; kt < 4; ++kt) {
    int i = l & 15;
    int row = ((kt >> 1) << 5) + ((kt & 1) << 2) + ((i >> 2) << 3) + (i & 3);
#pragma unroll
    for (int ks = 0; ks < 2; ++ks)
      koff[kt][ks] = swzoff(row, ks * 64 + ((l >> 4) << 4));
  }
  int voff[4][2];
#pragma unroll
  for (int dt = 0; dt < 4; ++dt)
#pragma unroll
    for (int ks = 0; ks < 2; ++ks)
      voff[dt][ks] = swzoff(dt * 16 + (l & 15), ks * 64 + ((l >> 4) << 4));

  f4_t acc[4][2] = {};                 // O^T: rows d, cols q(lane&15)
  float mrun[2] = {-1e30f, -1e30f};
  float lsum[2] = {0.0f, 0.0f};        // per-lane PARTIAL sum (reduced in epilogue)
  int cur = 0;

  for (int t = 0; t < 32; ++t) {
    // prefetch next K/V tile into the other buffer (overlaps with compute below)
    if (t < 31) {
      int kv0 = (t + 1) * 64;
      char* dK = lsK[cur ^ 1];
      char* dV = lsV[cur ^ 1];
#pragma unroll
      for (int u = 0; u < 2; ++u) {
        int p = (u * 256 + tid) * 16;
        int r = p >> 7, cb = p & 127;
        int c = cb ^ swm(r);
        async16((const char*)kg + (qkbase + (size_t)(kv0 + r) * 64) * 2 + c, dK + p);
        async16((const char*)vtg + (vtbase + (size_t)r * 2048 + kv0) * 2 + c, dV + p);
      }
    }
    const char* bK = lsK[cur];
    const char* bV = lsV[cur];

    // ---- QK^T (S^T) with permuted K-row feed ----
    f4_t sacc[4][2] = {};
#pragma unroll
    for (int kt = 0; kt < 4; ++kt)
#pragma unroll
      for (int ks = 0; ks < 2; ++ks) {
        bf8_t a = *(const bf8_t*)(bK + koff[kt][ks]);
#pragma unroll
        for (int qt = 0; qt < 2; ++qt)
          sacc[kt][qt] = __builtin_amdgcn_mfma_f32_16x16x32_bf16(
              a, qf[qt][ks], sacc[kt][qt], 0, 0, 0);
      }
    // lane holds, per qt: p for kv = 32*ks + 8*(l>>4) + (4*(kt&1)+j)

    // ---- online softmax (log2 domain; Q pre-scaled by SCALE*log2e) ----
    bf8_t pf[2][2];   // [ks][qt] : PV B-frags
#pragma unroll
    for (int qt = 0; qt < 2; ++qt) {
      float tm = sacc[0][qt][0];
#pragma unroll
      for (int kt = 0; kt < 4; ++kt)
#pragma unroll
        for (int jj = 0; jj < 4; ++jj) tm = fmaxf(tm, sacc[kt][qt][jj]);
      tm = fmaxf(tm, __shfl_xor(tm, 16));
      tm = fmaxf(tm, __shfl_xor(tm, 32));
      // defer-max: only rescale when some row max grew by > 8 (log2 domain)
      if (__any(tm > mrun[qt] + 8.0f)) {
        float mnew = fmaxf(mrun[qt], tm);
        float resc = __builtin_amdgcn_exp2f(mrun[qt] - mnew);
        mrun[qt] = mnew;
        lsum[qt] *= resc;
#pragma unroll
        for (int dt = 0; dt < 4; ++dt)
#pragma unroll
          for (int jj = 0; jj < 4; ++jj) acc[dt][qt][jj] *= resc;
      }
      float m = mrun[qt];
      float p[4][4];
      float ps = 0.0f;
#pragma unroll
      for (int kt = 0; kt < 4; ++kt)
#pragma unroll
        for (int jj = 0; jj < 4; ++jj) {
          p[kt][jj] = __builtin_amdgcn_exp2f(sacc[kt][qt][jj] - m);
          ps += p[kt][jj];
        }
      lsum[qt] += ps;   // per-lane partial
      // pack: B-frag element e (k = 8*(l>>4)+e) <- p[kt=2ks+(e>>2)][e&3]
#pragma unroll
      for (int ks = 0; ks < 2; ++ks)
#pragma unroll
        for (int e = 0; e < 8; ++e)
          pf[ks][qt][e] = (__bf16)p[2 * ks + (e >> 2)][e & 3];
    }

    // ---- PV: O^T += V^T-rows x P ----
#pragma unroll
    for (int dt = 0; dt < 4; ++dt) {
      bf8_t av0 = *(const bf8_t*)(bV + voff[dt][0]);
      bf8_t av1 = *(const bf8_t*)(bV + voff[dt][1]);
#pragma unroll
      for (int qt = 0; qt < 2; ++qt) {
        acc[dt][qt] = __builtin_amdgcn_mfma_f32_16x16x32_bf16(av0, pf[0][qt],
                                                              acc[dt][qt], 0, 0, 0);
        acc[dt][qt] = __builtin_amdgcn_mfma_f32_16x16x32_bf16(av1, pf[1][qt],
                                                              acc[dt][qt], 0, 0, 0);
      }
    }
    __syncthreads();   // all waves done reading buf cur; prefetch into cur^1 drained
    cur ^= 1;
  }

  // ---- epilogue: reduce partial sums, write attn_out[b][s][h*64+d] = O^T / lsum ----
#pragma unroll
  for (int qt = 0; qt < 2; ++qt) {
    lsum[qt] += __shfl_xor(lsum[qt], 16);
    lsum[qt] += __shfl_xor(lsum[qt], 32);
  }
  const int bb = bh / 12, h = bh % 12;
#pragma unroll
  for (int qt = 0; qt < 2; ++qt) {
    float inv = 1.0f / lsum[qt];
    int s = q0 + w * 32 + qt * 16 + (l & 15);
#pragma unroll
    for (int dt = 0; dt < 4; ++dt) {
      int dg = h * 64 + dt * 16 + ((l >> 4) << 2);
      ushort4 o;
      o.x = f2bf(acc[dt][qt][0] * inv);
      o.y = f2bf(acc[dt][qt][1] * inv);
      o.z = f2bf(acc[dt][qt][2] * inv);
      o.w = f2bf(acc[dt][qt][3] * inv);
      *(ushort4*)(attnb + ((size_t)(bb * 2048 + s)) * 768 + dg) = o;
    }
  }
}

extern "C" void kernel_launch(void* const* d_in, const int* in_sizes, int n_in,
                              void* d_out, int out_size, void* d_ws, size_t ws_size,
                              hipStream_t stream) {
  const float* x  = (const float*)d_in[0];
  const float* Wq = (const float*)d_in[1];
  const float* bq = (const float*)d_in[2];
  const float* Wk = (const float*)d_in[3];
  const float* bk = (const float*)d_in[4];
  const float* Wv = (const float*)d_in[5];
  const float* bv = (const float*)d_in[6];
  const float* Wo = (const float*)d_in[7];
  const float* bo = (const float*)d_in[8];

  const size_t XB_ELEMS = (size_t)8192 * 768;   // 6291456
  const size_t W_ELEMS  = (size_t)768 * 768;    // 589824
  unsigned short* xb  = (unsigned short*)d_ws;
  unsigned short* wqb = xb  + XB_ELEMS;
  unsigned short* wkb = wqb + W_ELEMS;
  unsigned short* wvb = wkb + W_ELEMS;
  unsigned short* wob = wvb + W_ELEMS;
  unsigned short* qb  = wob + W_ELEMS;
  unsigned short* kb  = qb  + XB_ELEMS;
  unsigned short* vtb = kb  + XB_ELEMS;
  unsigned short* attnb = xb;   // alias: xb dead after proj_qkv

  cvt_kernel<<<2048, 256, 0, stream>>>(x, xb, (int)(XB_ELEMS / 4));
  cvt4_kernel<<<dim3(144, 4), 256, 0, stream>>>(Wq, Wk, Wv, Wo,
                                                wqb, wkb, wvb, wob,
                                                (int)(W_ELEMS / 4));

  proj_qkv<<<1152, 256, 0, stream>>>(xb, wqb, wkb, wvb, bq, bk, bv, qb, kb, vtb);
  attn_kernel<<<dim3(16, 48), 256, 0, stream>>>(qb, kb, vtb, attnb);
  proj_o<<<384, 256, 0, stream>>>(attnb, wob, bo, (float*)d_out);
}

// Round 3
// 168.102 us; speedup vs baseline: 1.2922x; 1.0562x over previous
//
#include <hip/hip_runtime.h>

// Problem constants: B=4, S=2048, D=768, H=12, HD=64, M=B*S=8192, K=768.
#define LOG2E 1.4426950408889634f
#define QSCALE (0.125f * LOG2E)   // HD^-0.5 * log2(e), folded into Q

typedef __attribute__((ext_vector_type(8))) __bf16 bf8_t;   // MFMA A/B frag (4 VGPR)
typedef __attribute__((ext_vector_type(4))) float f4_t;     // MFMA C/D frag

__device__ __forceinline__ unsigned short f2bf(float f) {
  unsigned int u = __float_as_uint(f);
  u += 0x7fff + ((u >> 16) & 1);          // RNE
  return (unsigned short)(u >> 16);
}

__device__ __forceinline__ void async16(const void* g, void* l) {
  __builtin_amdgcn_global_load_lds(
      (const __attribute__((address_space(1))) void*)g,
      (__attribute__((address_space(3))) void*)l, 16, 0, 0);
}

// XOR swizzle for 128B LDS rows: spreads 16 consecutive (or kt-permuted) rows
// over 8 distinct 16B slots -> 2-way conflict (free). Involution on 16B units.
__device__ __forceinline__ int swm(int r) {
  return ((r & 3) << 4) | ((r & 8) << 3);
}
__device__ __forceinline__ int swzoff(int row, int cb) {
  return (row << 7) + (cb ^ swm(row));
}

// ---------------- fp32 -> bf16 conversion ----------------
__global__ void cvt_kernel(const float* __restrict__ src,
                           unsigned short* __restrict__ dst, int n4) {
  int i = blockIdx.x * blockDim.x + threadIdx.x;
  int stride = gridDim.x * blockDim.x;
  for (; i < n4; i += stride) {
    float4 v = ((const float4*)src)[i];
    ushort4 o;
    o.x = f2bf(v.x); o.y = f2bf(v.y); o.z = f2bf(v.z); o.w = f2bf(v.w);
    ((ushort4*)dst)[i] = o;
  }
}

// 4 weight matrices in one launch (blockIdx.y selects)
__global__ void cvt4_kernel(const float* __restrict__ s0, const float* __restrict__ s1,
                            const float* __restrict__ s2, const float* __restrict__ s3,
                            unsigned short* __restrict__ d0, unsigned short* __restrict__ d1,
                            unsigned short* __restrict__ d2, unsigned short* __restrict__ d3,
                            int n4) {
  int z = blockIdx.y;
  const float* s = (z == 0) ? s0 : (z == 1) ? s1 : (z == 2) ? s2 : s3;
  unsigned short* d = (z == 0) ? d0 : (z == 1) ? d1 : (z == 2) ? d2 : d3;
  int i = blockIdx.x * blockDim.x + threadIdx.x;
  int stride = gridDim.x * blockDim.x;
  for (; i < n4; i += stride) {
    float4 v = ((const float4*)s)[i];
    ushort4 o;
    o.x = f2bf(v.x); o.y = f2bf(v.y); o.z = f2bf(v.z); o.w = f2bf(v.w);
    ((ushort4*)d)[i] = o;
  }
}

// ---------------- shared NT-GEMM core ----------------
// D[i][j] = sum_k A[i][k] * Bm[j][k], K=768, tile 128x128, BK=64, 4 waves 2x2.
// C/D layout: col(j) = lane&15, row(i) = (lane>>4)*4 + reg.
__device__ __forceinline__ void gemm_core(const unsigned short* __restrict__ A,
                                          const unsigned short* __restrict__ Bm,
                                          int i0, int j0,
                                          char* lsA, char* lsB,
                                          f4_t (&acc)[4][4]) {
  const int tid = threadIdx.x;
  const int l = tid & 63;
  const int wi = (tid >> 6) >> 1, wj = (tid >> 6) & 1;
  for (int k0 = 0; k0 < 768; k0 += 64) {
    // stage A/B tiles (16KB each), linear LDS dest + inverse-swizzled source
#pragma unroll
    for (int u = 0; u < 4; ++u) {
      int p = (u * 256 + tid) * 16;
      int r = p >> 7, cb = p & 127;
      int c = cb ^ swm(r);
      async16((const char*)A + ((size_t)(i0 + r) * 768 + k0) * 2 + c, lsA + p);
      async16((const char*)Bm + ((size_t)(j0 + r) * 768 + k0) * 2 + c, lsB + p);
    }
    __syncthreads();   // drains vmcnt -> tiles ready
#pragma unroll
    for (int ks = 0; ks < 2; ++ks) {
      bf8_t af[4], bfr[4];
#pragma unroll
      for (int mi = 0; mi < 4; ++mi)
        af[mi] = *(const bf8_t*)(lsA + swzoff(wi * 64 + mi * 16 + (l & 15),
                                              ks * 64 + ((l >> 4) << 4)));
#pragma unroll
      for (int nj = 0; nj < 4; ++nj)
        bfr[nj] = *(const bf8_t*)(lsB + swzoff(wj * 64 + nj * 16 + (l & 15),
                                               ks * 64 + ((l >> 4) << 4)));
      __builtin_amdgcn_s_setprio(1);
#pragma unroll
      for (int mi = 0; mi < 4; ++mi)
#pragma unroll
        for (int nj = 0; nj < 4; ++nj)
          acc[mi][nj] = __builtin_amdgcn_mfma_f32_16x16x32_bf16(
              af[mi], bfr[nj], acc[mi][nj], 0, 0, 0);
      __builtin_amdgcn_s_setprio(0);
    }
    __syncthreads();   // LDS reuse protection
  }
}

// ---------------- QKV projection ----------------
// z=0: Q = (x Wq^T + bq)*QSCALE -> [B,H,S,64] bf16   (A=Wq, Bm=xb, i=n, j=m)
// z=1: K = (x Wk^T + bk)        -> [B,H,S,64] bf16
// z=2: V = (x Wv^T + bv)        -> [B,H,64,S] bf16 (transposed; A=xb, Bm=Wv, i=m, j=n)
__global__ __launch_bounds__(256) void proj_qkv(
    const unsigned short* __restrict__ xb,
    const unsigned short* __restrict__ wq,
    const unsigned short* __restrict__ wk,
    const unsigned short* __restrict__ wv,
    const float* __restrict__ bq, const float* __restrict__ bk,
    const float* __restrict__ bv,
    unsigned short* __restrict__ qo, unsigned short* __restrict__ ko,
    unsigned short* __restrict__ vto) {
  __shared__ char lsA[16384], lsB[16384];
  // XCD-aware bijective swizzle: 1152 = 8 * 144 -> consecutive logical blocks
  // (sharing B-panels) land on the same XCD's L2.
  const int bx = (blockIdx.x & 7) * 144 + (blockIdx.x >> 3);
  const int z = bx / 384, r = bx % 384;
  int it, jt;
  const unsigned short *A, *Bm;
  const float* bias;
  if (z == 0)      { A = wq; Bm = xb; bias = bq; it = r % 6;  jt = r / 6;  }
  else if (z == 1) { A = wk; Bm = xb; bias = bk; it = r % 6;  jt = r / 6;  }
  else             { A = xb; Bm = wv; bias = bv; it = r % 64; jt = r / 64; }
  const int i0 = it * 128, j0 = jt * 128;
  f4_t acc[4][4] = {};
  gemm_core(A, Bm, i0, j0, lsA, lsB, acc);

  const int tid = threadIdx.x, l = tid & 63;
  const int wi = (tid >> 6) >> 1, wj = (tid >> 6) & 1;
#pragma unroll
  for (int mi = 0; mi < 4; ++mi) {
#pragma unroll
    for (int nj = 0; nj < 4; ++nj) {
      int ib = i0 + wi * 64 + mi * 16 + ((l >> 4) << 2);  // i, 4 consecutive
      int j  = j0 + wj * 64 + nj * 16 + (l & 15);         // j
      f4_t v = acc[mi][nj];
      if (z < 2) {
        float4 bs = *(const float4*)(bias + ib);
        float sc = (z == 0) ? QSCALE : 1.0f;
        ushort4 o;
        o.x = f2bf((v[0] + bs.x) * sc);
        o.y = f2bf((v[1] + bs.y) * sc);
        o.z = f2bf((v[2] + bs.z) * sc);
        o.w = f2bf((v[3] + bs.w) * sc);
        int bb = j >> 11, s = j & 2047;
        int h = ib >> 6, d = ib & 63;
        unsigned short* dst = (z == 0) ? qo : ko;
        *(ushort4*)(dst + (((size_t)(bb * 12 + h) * 2048 + s) << 6) + d) = o;
      } else {
        float bvs = bias[j];
        ushort4 o;
        o.x = f2bf(v[0] + bvs); o.y = f2bf(v[1] + bvs);
        o.z = f2bf(v[2] + bvs); o.w = f2bf(v[3] + bvs);
        int bb = ib >> 11, s4 = ib & 2047;   // i is the m-dim here
        int h = j >> 6, d = j & 63;
        *(ushort4*)(vto + ((size_t)((bb * 12 + h) * 64 + d)) * 2048 + s4) = o;
      }
    }
  }
}

// ---------------- output projection: out = attn @ Wo^T + bo (fp32 out) ----------------
__global__ __launch_bounds__(256) void proj_o(
    const unsigned short* __restrict__ attnb, const unsigned short* __restrict__ wo,
    const float* __restrict__ bo, float* __restrict__ outp) {
  __shared__ char lsA[16384], lsB[16384];
  const int bx = (blockIdx.x & 7) * 48 + (blockIdx.x >> 3);  // 384 = 8*48
  const int it = bx % 6, jt = bx / 6;
  const int i0 = it * 128, j0 = jt * 128;
  f4_t acc[4][4] = {};
  gemm_core(wo, attnb, i0, j0, lsA, lsB, acc);
  const int tid = threadIdx.x, l = tid & 63;
  const int wi = (tid >> 6) >> 1, wj = (tid >> 6) & 1;
#pragma unroll
  for (int mi = 0; mi < 4; ++mi) {
#pragma unroll
    for (int nj = 0; nj < 4; ++nj) {
      int ib = i0 + wi * 64 + mi * 16 + ((l >> 4) << 2);  // n, 4 consecutive
      int j  = j0 + wj * 64 + nj * 16 + (l & 15);         // m
      float4 bs = *(const float4*)(bo + ib);
      float4 o;
      o.x = acc[mi][nj][0] + bs.x;
      o.y = acc[mi][nj][1] + bs.y;
      o.z = acc[mi][nj][2] + bs.z;
      o.w = acc[mi][nj][3] + bs.w;
      *(float4*)(outp + (size_t)j * 768 + ib) = o;
    }
  }
}

// ---------------- flash attention ----------------
// Block: 128 q rows of one (b,h); 8 waves x 16 q-cols each (512 thr). KV tile = 64,
// double-buffered. S^T = mfma(K_rows, Q_rows): C col = q (lane&15), row = kv.
// K rows fed permuted per-mfma so P lands directly in PV's B-frag layout.
__global__ __launch_bounds__(512) void attn_kernel(
    const unsigned short* __restrict__ qg,
    const unsigned short* __restrict__ kg,
    const unsigned short* __restrict__ vtg,
    unsigned short* __restrict__ attnb) {
  __shared__ char lsQ[16384];     // [128][64] bf16, swizzled
  __shared__ char lsK[2][8192];   // [64][64] double-buffered
  __shared__ char lsV[2][8192];   // V^T tile: [64 d][64 kv]
  const int tid = threadIdx.x, l = tid & 63, w = tid >> 6;   // w in 0..7
  // XCD-aware 1D swizzle: 768 = 8*96; groups all 16 q-blocks of a bh on one XCD.
  const int swz = (blockIdx.x & 7) * 96 + (blockIdx.x >> 3);
  const int q0 = (swz & 15) * 128;
  const int bh = swz >> 4;
  const size_t qkbase = (size_t)bh * 2048 * 64;
  const size_t vtbase = (size_t)bh * 64 * 2048;

  // stage Q tile (16KB, two rounds of 512x16B)
#pragma unroll
  for (int u = 0; u < 2; ++u) {
    int p = (u * 512 + tid) * 16;
    int r = p >> 7, cb = p & 127;
    int c = cb ^ swm(r);
    async16((const char*)qg + (qkbase + (size_t)(q0 + r) * 64) * 2 + c, lsQ + p);
  }
  // stage K/V tile 0 into buf 0 (8KB each, one round)
  const int p16 = tid * 16;
  const int sr = p16 >> 7, scb = p16 & 127;
  const int sc = scb ^ swm(sr);
  async16((const char*)kg + (qkbase + (size_t)sr * 64) * 2 + sc, lsK[0] + p16);
  async16((const char*)vtg + (vtbase + (size_t)sr * 2048) * 2 + sc, lsV[0] + p16);
  __syncthreads();

  // hoisted per-thread global staging pointers (start at tile 1)
  const char* gK = (const char*)kg + (qkbase + (size_t)(64 + sr) * 64) * 2 + sc;
  const char* gV = (const char*)vtg + (vtbase + (size_t)sr * 2048 + 64) * 2 + sc;

  bf8_t qf[2];
#pragma unroll
  for (int ks = 0; ks < 2; ++ks)
    qf[ks] = *(const bf8_t*)(lsQ + swzoff(w * 16 + (l & 15),
                                          ks * 64 + ((l >> 4) << 4)));

  // hoisted LDS read offsets (invariant across tiles)
  int koff[4][2];
#pragma unroll
  for (int kt = 0; kt < 4; ++kt) {
    int i = l & 15;
    int row = ((kt >> 1) << 5) + ((kt & 1) << 2) + ((i >> 2) << 3) + (i & 3);
#pragma unroll
    for (int ks = 0; ks < 2; ++ks)
      koff[kt][ks] = swzoff(row, ks * 64 + ((l >> 4) << 4));
  }
  int voff[4][2];
#pragma unroll
  for (int dt = 0; dt < 4; ++dt)
#pragma unroll
    for (int ks = 0; ks < 2; ++ks)
      voff[dt][ks] = swzoff(dt * 16 + (l & 15), ks * 64 + ((l >> 4) << 4));

  f4_t acc[4] = {};                 // O^T: rows d, cols q(lane&15)
  float mrun = -1e30f;
  float lsum = 0.0f;                // per-lane PARTIAL sum (reduced in epilogue)
  int cur = 0;

  for (int t = 0; t < 32; ++t) {
    // prefetch next K/V tile into the other buffer (overlaps with compute below)
    if (t < 31) {
      async16(gK, lsK[cur ^ 1] + p16);
      async16(gV, lsV[cur ^ 1] + p16);
      gK += 8192;   // 64 rows * 128B
      gV += 128;    // 64 cols * 2B
    }
    const char* bK = lsK[cur];
    const char* bV = lsV[cur];

    // ---- QK^T (S^T) with permuted K-row feed ----
    f4_t sacc[4] = {};
    __builtin_amdgcn_s_setprio(1);
#pragma unroll
    for (int kt = 0; kt < 4; ++kt)
#pragma unroll
      for (int ks = 0; ks < 2; ++ks) {
        bf8_t a = *(const bf8_t*)(bK + koff[kt][ks]);
        sacc[kt] = __builtin_amdgcn_mfma_f32_16x16x32_bf16(
            a, qf[ks], sacc[kt], 0, 0, 0);
      }
    __builtin_amdgcn_s_setprio(0);
    // lane holds p for kv = 32*ks + 8*(l>>4) + (4*(kt&1)+j)

    // ---- online softmax (log2 domain; Q pre-scaled by SCALE*log2e) ----
    // tree max over 16 values (max3-fusable nests, short dep chain)
    float m01 = fmaxf(fmaxf(sacc[0][0], sacc[0][1]), fmaxf(sacc[0][2], sacc[0][3]));
    float m23 = fmaxf(fmaxf(sacc[1][0], sacc[1][1]), fmaxf(sacc[1][2], sacc[1][3]));
    float m45 = fmaxf(fmaxf(sacc[2][0], sacc[2][1]), fmaxf(sacc[2][2], sacc[2][3]));
    float m67 = fmaxf(fmaxf(sacc[3][0], sacc[3][1]), fmaxf(sacc[3][2], sacc[3][3]));
    float tm = fmaxf(fmaxf(m01, m23), fmaxf(m45, m67));
    tm = fmaxf(tm, __shfl_xor(tm, 16));
    tm = fmaxf(tm, __shfl_xor(tm, 32));
    // defer-max: only rescale when some row max grew by > 8 (log2 domain)
    if (__any(tm > mrun + 8.0f)) {
      float mnew = fmaxf(mrun, tm);
      float resc = __builtin_amdgcn_exp2f(mrun - mnew);
      mrun = mnew;
      lsum *= resc;
#pragma unroll
      for (int dt = 0; dt < 4; ++dt)
#pragma unroll
        for (int jj = 0; jj < 4; ++jj) acc[dt][jj] *= resc;
    }
    float p[4][4];
#pragma unroll
    for (int kt = 0; kt < 4; ++kt)
#pragma unroll
      for (int jj = 0; jj < 4; ++jj)
        p[kt][jj] = __builtin_amdgcn_exp2f(sacc[kt][jj] - mrun);
    // tree sum
    float s0 = (p[0][0] + p[0][1]) + (p[0][2] + p[0][3]);
    float s1 = (p[1][0] + p[1][1]) + (p[1][2] + p[1][3]);
    float s2 = (p[2][0] + p[2][1]) + (p[2][2] + p[2][3]);
    float s3 = (p[3][0] + p[3][1]) + (p[3][2] + p[3][3]);
    lsum += (s0 + s1) + (s2 + s3);
    // pack: B-frag element e (k = 8*(l>>4)+e) <- p[kt=2ks+(e>>2)][e&3]
    bf8_t pf[2];
#pragma unroll
    for (int ks = 0; ks < 2; ++ks)
#pragma unroll
      for (int e = 0; e < 8; ++e)
        pf[ks][e] = (__bf16)p[2 * ks + (e >> 2)][e & 3];

    // ---- PV: O^T += V^T-rows x P ----
    __builtin_amdgcn_s_setprio(1);
#pragma unroll
    for (int dt = 0; dt < 4; ++dt) {
      bf8_t av0 = *(const bf8_t*)(bV + voff[dt][0]);
      bf8_t av1 = *(const bf8_t*)(bV + voff[dt][1]);
      acc[dt] = __builtin_amdgcn_mfma_f32_16x16x32_bf16(av0, pf[0], acc[dt], 0, 0, 0);
      acc[dt] = __builtin_amdgcn_mfma_f32_16x16x32_bf16(av1, pf[1], acc[dt], 0, 0, 0);
    }
    __builtin_amdgcn_s_setprio(0);
    __syncthreads();   // all waves done reading buf cur; prefetch into cur^1 drained
    cur ^= 1;
  }

  // ---- epilogue: reduce partial sums, write attn_out[b][s][h*64+d] = O^T / lsum ----
  lsum += __shfl_xor(lsum, 16);
  lsum += __shfl_xor(lsum, 32);
  const int bb = bh / 12, h = bh % 12;
  float inv = 1.0f / lsum;
  int s = q0 + w * 16 + (l & 15);
#pragma unroll
  for (int dt = 0; dt < 4; ++dt) {
    int dg = h * 64 + dt * 16 + ((l >> 4) << 2);
    ushort4 o;
    o.x = f2bf(acc[dt][0] * inv);
    o.y = f2bf(acc[dt][1] * inv);
    o.z = f2bf(acc[dt][2] * inv);
    o.w = f2bf(acc[dt][3] * inv);
    *(ushort4*)(attnb + ((size_t)(bb * 2048 + s)) * 768 + dg) = o;
  }
}

extern "C" void kernel_launch(void* const* d_in, const int* in_sizes, int n_in,
                              void* d_out, int out_size, void* d_ws, size_t ws_size,
                              hipStream_t stream) {
  const float* x  = (const float*)d_in[0];
  const float* Wq = (const float*)d_in[1];
  const float* bq = (const float*)d_in[2];
  const float* Wk = (const float*)d_in[3];
  const float* bk = (const float*)d_in[4];
  const float* Wv = (const float*)d_in[5];
  const float* bv = (const float*)d_in[6];
  const float* Wo = (const float*)d_in[7];
  const float* bo = (const float*)d_in[8];

  const size_t XB_ELEMS = (size_t)8192 * 768;   // 6291456
  const size_t W_ELEMS  = (size_t)768 * 768;    // 589824
  unsigned short* xb  = (unsigned short*)d_ws;
  unsigned short* wqb = xb  + XB_ELEMS;
  unsigned short* wkb = wqb + W_ELEMS;
  unsigned short* wvb = wkb + W_ELEMS;
  unsigned short* wob = wvb + W_ELEMS;
  unsigned short* qb  = wob + W_ELEMS;
  unsigned short* kb  = qb  + XB_ELEMS;
  unsigned short* vtb = kb  + XB_ELEMS;
  unsigned short* attnb = xb;   // alias: xb dead after proj_qkv

  cvt_kernel<<<2048, 256, 0, stream>>>(x, xb, (int)(XB_ELEMS / 4));
  cvt4_kernel<<<dim3(144, 4), 256, 0, stream>>>(Wq, Wk, Wv, Wo,
                                                wqb, wkb, wvb, wob,
                                                (int)(W_ELEMS / 4));

  proj_qkv<<<1152, 256, 0, stream>>>(xb, wqb, wkb, wvb, bq, bk, bv, qb, kb, vtb);
  attn_kernel<<<768, 512, 0, stream>>>(qb, kb, vtb, attnb);
  proj_o<<<384, 256, 0, stream>>>(attnb, wob, bo, (float*)d_out);
}